// Round 1
// baseline (22676.006 us; speedup 1.0000x reference)
//
#include <hip/hip_runtime.h>
#include <math.h>

#define LAYERS 12
#define NHEAD  12
#define EMB    768
#define VOCAB  50257
#define BATCH  2
#define SEQ    1024
#define HDIM   64
#define FFDIM  3072
#define MTOK   (BATCH*SEQ)   /* 2048 */
#define EPSLN  1e-5f

// ---------------- helpers ----------------
__device__ inline float waveRedSum(float v) {
#pragma unroll
    for (int o = 32; o > 0; o >>= 1) v += __shfl_xor(v, o, 64);
    return v;
}
__device__ inline float waveRedMax(float v) {
#pragma unroll
    for (int o = 32; o > 0; o >>= 1) v = fmaxf(v, __shfl_xor(v, o, 64));
    return v;
}

// ---------------- embedding: h = tok_emb[idx] + pos_emb ----------------
__global__ __launch_bounds__(192) void embed_k(const int* __restrict__ idx,
                                               const float* __restrict__ tok,
                                               const float* __restrict__ pos,
                                               float* __restrict__ h) {
    int row = blockIdx.x;            // 0..MTOK-1
    int s = row % SEQ;
    int t = idx[row];
    const float4* te = (const float4*)(tok + (size_t)t * EMB);
    const float4* pe = (const float4*)(pos + (size_t)s * EMB);
    float4* o = (float4*)(h + (size_t)row * EMB);
    int i = threadIdx.x;             // 192 threads, EMB/4 = 192
    float4 a = te[i], b = pe[i];
    o[i] = make_float4(a.x + b.x, a.y + b.y, a.z + b.z, a.w + b.w);
}

// ---------------- layernorm: one block per row ----------------
__global__ __launch_bounds__(256) void ln_k(const float* __restrict__ x,
                                            const float* __restrict__ g,
                                            const float* __restrict__ b,
                                            float* __restrict__ o) {
    int row = blockIdx.x;
    int t = threadIdx.x;
    const float* xr = x + (size_t)row * EMB;
    float a0 = xr[t], a1 = xr[t + 256], a2 = xr[t + 512];
    __shared__ float red[4];
    float s = waveRedSum(a0 + a1 + a2);
    if ((t & 63) == 0) red[t >> 6] = s;
    __syncthreads();
    float mean = (red[0] + red[1] + red[2] + red[3]) * (1.0f / EMB);
    float d0 = a0 - mean, d1 = a1 - mean, d2 = a2 - mean;
    float vv = waveRedSum(d0 * d0 + d1 * d1 + d2 * d2);
    __syncthreads();
    if ((t & 63) == 0) red[t >> 6] = vv;
    __syncthreads();
    float var = (red[0] + red[1] + red[2] + red[3]) * (1.0f / EMB);
    float rstd = rsqrtf(var + EPSLN);
    float* orow = o + (size_t)row * EMB;
    orow[t]       = d0 * rstd * g[t]       + b[t];
    orow[t + 256] = d1 * rstd * g[t + 256] + b[t + 256];
    orow[t + 512] = d2 * rstd * g[t + 512] + b[t + 512];
}

// ---------------- fp32 tiled GEMM: C[M,N] = A[M,K] @ B[K,N] (+bias)(+gelu)(+res) ----
// 64x64 tile, BK=16, 256 threads, 4x4 microtile. M is always a multiple of 64.
__global__ __launch_bounds__(256) void gemm_k(const float* __restrict__ A,
                                              const float* __restrict__ Bw,
                                              const float* __restrict__ bias,
                                              const float* __restrict__ Res,
                                              float* __restrict__ C,
                                              int N, int K, int applyGelu) {
    __shared__ float Ast[16][68];   // K-major A tile (transposed on store)
    __shared__ float Bs[16][64];
    const int t = threadIdx.x;
    const int row0 = blockIdx.y * 64, col0 = blockIdx.x * 64;
    const int tx = t & 15, ty = t >> 4;
    const int arow = t >> 2, ak = (t & 3) << 2;      // A tile: 64 rows x 16 k
    const int brow = t >> 4, bc = (t & 15) << 2;     // B tile: 16 rows x 64 cols
    float acc[4][4] = {};
    const float* aptr = A + (size_t)(row0 + arow) * K + ak;
    const int bcol = col0 + bc;

    for (int k0 = 0; k0 < K; k0 += 16) {
        float4 av = *(const float4*)(aptr + k0);
        Ast[ak + 0][arow] = av.x;
        Ast[ak + 1][arow] = av.y;
        Ast[ak + 2][arow] = av.z;
        Ast[ak + 3][arow] = av.w;
        const float* bp = Bw + (size_t)(k0 + brow) * N + bcol;
        float4 bv;
        if (bcol + 3 < N) {
            bv = *(const float4*)bp;
        } else {
            bv.x = (bcol + 0 < N) ? bp[0] : 0.f;
            bv.y = (bcol + 1 < N) ? bp[1] : 0.f;
            bv.z = (bcol + 2 < N) ? bp[2] : 0.f;
            bv.w = (bcol + 3 < N) ? bp[3] : 0.f;
        }
        *(float4*)&Bs[brow][bc] = bv;
        __syncthreads();
#pragma unroll
        for (int kk = 0; kk < 16; ++kk) {
            float4 a = *(const float4*)&Ast[kk][ty << 2];
            float4 b = *(const float4*)&Bs[kk][tx << 2];
            acc[0][0] += a.x * b.x; acc[0][1] += a.x * b.y; acc[0][2] += a.x * b.z; acc[0][3] += a.x * b.w;
            acc[1][0] += a.y * b.x; acc[1][1] += a.y * b.y; acc[1][2] += a.y * b.z; acc[1][3] += a.y * b.w;
            acc[2][0] += a.z * b.x; acc[2][1] += a.z * b.y; acc[2][2] += a.z * b.z; acc[2][3] += a.z * b.w;
            acc[3][0] += a.w * b.x; acc[3][1] += a.w * b.y; acc[3][2] += a.w * b.z; acc[3][3] += a.w * b.w;
        }
        __syncthreads();
    }
#pragma unroll
    for (int i = 0; i < 4; ++i) {
        int row = row0 + (ty << 2) + i;
#pragma unroll
        for (int j = 0; j < 4; ++j) {
            int col = col0 + (tx << 2) + j;
            if (col < N) {
                float v = acc[i][j];
                if (bias) v += bias[col];
                if (applyGelu) {
                    float xg = v;
                    v = 0.5f * xg * (1.f + tanhf(0.7978845608028654f * (xg + 0.044715f * xg * xg * xg)));
                }
                if (Res) v += Res[(size_t)row * N + col];
                C[(size_t)row * N + col] = v;
            }
        }
    }
}

// ---------------- causal attention, one block per (b, h, q-row) ----------------
__global__ __launch_bounds__(256) void attn_k(const float* __restrict__ Q,
                                              const float* __restrict__ Kb,
                                              const float* __restrict__ Vb,
                                              float* __restrict__ O) {
    int blk = blockIdx.x;
    int qi = blk & (SEQ - 1);
    int hh = (blk >> 10) % NHEAD;
    int bb = blk / (SEQ * NHEAD);
    int t = threadIdx.x;
    int lane = t & 63, wave = t >> 6;
    __shared__ float qs[HDIM];
    __shared__ float sc[SEQ];
    __shared__ float red[4], red2[4];
    __shared__ float vred[4][HDIM];
    const size_t headOff = (size_t)bb * SEQ * EMB + (size_t)hh * HDIM;
    if (t < HDIM) qs[t] = Q[headOff + (size_t)qi * EMB + t] * 0.125f;  // scale = HD^-0.5
    __syncthreads();
    int nk = qi + 1;
    // scores: one wave per key, coalesced 64-float K row load, shuffle-reduce dot
    for (int kk = wave; kk < nk; kk += 4) {
        float kv = Kb[headOff + (size_t)kk * EMB + lane];
        float p = waveRedSum(qs[lane] * kv);
        if (lane == 0) sc[kk] = p;
    }
    __syncthreads();
    // softmax over sc[0..nk)
    float m = -1e30f;
    for (int kk = t; kk < nk; kk += 256) m = fmaxf(m, sc[kk]);
    m = waveRedMax(m);
    if (lane == 0) red[wave] = m;
    __syncthreads();
    m = fmaxf(fmaxf(red[0], red[1]), fmaxf(red[2], red[3]));
    float ssum = 0.f;
    for (int kk = t; kk < nk; kk += 256) {
        float p = __expf(sc[kk] - m);
        sc[kk] = p;
        ssum += p;
    }
    ssum = waveRedSum(ssum);
    if (lane == 0) red2[wave] = ssum;
    __syncthreads();
    float inv = 1.0f / (red2[0] + red2[1] + red2[2] + red2[3]);
    // PV: thread handles dim d, key chunk c; coalesced V row loads
    int d = t & 63, chunk = t >> 6;
    float acc = 0.f;
    for (int kk = chunk; kk < nk; kk += 4)
        acc += sc[kk] * Vb[headOff + (size_t)kk * EMB + d];
    vred[chunk][d] = acc;
    __syncthreads();
    if (t < HDIM) {
        float r = (vred[0][t] + vred[1][t] + vred[2][t] + vred[3][t]) * inv;
        O[headOff + (size_t)qi * EMB + t] = r;
    }
}

// ---------------- launch ----------------
extern "C" void kernel_launch(void* const* d_in, const int* in_sizes, int n_in,
                              void* d_out, int out_size, void* d_ws, size_t ws_size,
                              hipStream_t stream) {
    const int*   idx  = (const int*)d_in[0];
    const float* tok  = (const float*)d_in[1];
    const float* pos  = (const float*)d_in[2];
    const float* ln1g = (const float*)d_in[3];
    const float* ln1b = (const float*)d_in[4];
    const float* wq   = (const float*)d_in[5];
    const float* bq   = (const float*)d_in[6];
    const float* wk   = (const float*)d_in[7];
    const float* bk   = (const float*)d_in[8];
    const float* wv   = (const float*)d_in[9];
    const float* bv   = (const float*)d_in[10];
    const float* wo   = (const float*)d_in[11];
    const float* bo   = (const float*)d_in[12];
    const float* ln2g = (const float*)d_in[13];
    const float* ln2b = (const float*)d_in[14];
    const float* w1   = (const float*)d_in[15];
    const float* b1   = (const float*)d_in[16];
    const float* w2   = (const float*)d_in[17];
    const float* b2   = (const float*)d_in[18];
    const float* lnfg = (const float*)d_in[19];
    const float* lnfb = (const float*)d_in[20];
    const float* wout = (const float*)d_in[21];
    float* out = (float*)d_out;
    float* ws  = (float*)d_ws;

    const size_t ME = (size_t)MTOK * EMB;
    float* h  = ws;
    float* x  = h  + ME;
    float* qb = x  + ME;
    float* kb = qb + ME;
    float* vb = kb + ME;
    float* ao = vb + ME;
    float* ff = ao + ME;   // MTOK x FFDIM

    embed_k<<<MTOK, 192, 0, stream>>>(idx, tok, pos, h);

    for (int l = 0; l < LAYERS; ++l) {
        const size_t wOff = (size_t)l * EMB * EMB;
        ln_k<<<MTOK, 256, 0, stream>>>(h, ln1g + l * EMB, ln1b + l * EMB, x);
        gemm_k<<<dim3(EMB / 64, MTOK / 64), 256, 0, stream>>>(
            x, wq + wOff, bq + l * EMB, nullptr, qb, EMB, EMB, 0);
        gemm_k<<<dim3(EMB / 64, MTOK / 64), 256, 0, stream>>>(
            x, wk + wOff, bk + l * EMB, nullptr, kb, EMB, EMB, 0);
        gemm_k<<<dim3(EMB / 64, MTOK / 64), 256, 0, stream>>>(
            x, wv + wOff, bv + l * EMB, nullptr, vb, EMB, EMB, 0);
        attn_k<<<BATCH * NHEAD * SEQ, 256, 0, stream>>>(qb, kb, vb, ao);
        gemm_k<<<dim3(EMB / 64, MTOK / 64), 256, 0, stream>>>(
            ao, wo + wOff, bo + l * EMB, h, h, EMB, EMB, 0);
        ln_k<<<MTOK, 256, 0, stream>>>(h, ln2g + l * EMB, ln2b + l * EMB, x);
        gemm_k<<<dim3(FFDIM / 64, MTOK / 64), 256, 0, stream>>>(
            x, w1 + (size_t)l * EMB * FFDIM, b1 + (size_t)l * FFDIM, nullptr, ff, FFDIM, EMB, 1);
        gemm_k<<<dim3(EMB / 64, MTOK / 64), 256, 0, stream>>>(
            ff, w2 + (size_t)l * FFDIM * EMB, b2 + l * EMB, h, h, EMB, FFDIM, 0);
    }

    ln_k<<<MTOK, 256, 0, stream>>>(h, lnfg, lnfb, x);
    gemm_k<<<dim3((VOCAB + 63) / 64, MTOK / 64), 256, 0, stream>>>(
        x, wout, nullptr, nullptr, out, VOCAB, EMB, 0);
}

// Round 2
// 15880.408 us; speedup vs baseline: 1.4279x; 1.4279x over previous
//
#include <hip/hip_runtime.h>
#include <math.h>

#define LAYERS 12
#define NHEAD  12
#define EMB    768
#define VOCAB  50257
#define VPAD   50304          /* vocab padded to multiple of 128 */
#define BATCH  2
#define SEQ    1024
#define HDIM   64
#define FFDIM  3072
#define QKVN   (3*EMB)        /* 2304 */
#define MTOK   (BATCH*SEQ)    /* 2048 */
#define EPSLN  1e-5f

typedef __attribute__((ext_vector_type(8))) short short8;
typedef __attribute__((ext_vector_type(4))) float f32x4;

// ---------------- helpers ----------------
__device__ inline float waveRedSum(float v) {
#pragma unroll
    for (int o = 32; o > 0; o >>= 1) v += __shfl_xor(v, o, 64);
    return v;
}
__device__ inline float waveRedMax(float v) {
#pragma unroll
    for (int o = 32; o > 0; o >>= 1) v = fmaxf(v, __shfl_xor(v, o, 64));
    return v;
}
__device__ inline ushort f2bf(float x) {            // RNE fp32 -> bf16
    unsigned u = __float_as_uint(x);
    u += 0x7FFF + ((u >> 16) & 1);
    return (ushort)(u >> 16);
}
__device__ inline float geluf(float x) {
    float t = 0.7978845608028654f * (x + 0.044715f * x * x * x);
    float e = __expf(2.0f * t);
    float th = 1.0f - 2.0f / (e + 1.0f);
    return 0.5f * x * (1.0f + th);
}
__device__ inline void gload_lds16(const ushort* g, ushort* l) {
    __builtin_amdgcn_global_load_lds((const __attribute__((address_space(1))) char*)g,
                                     (__attribute__((address_space(3))) char*)l, 16, 0, 0);
}

// ---------------- embedding ----------------
__global__ __launch_bounds__(192) void embed_k(const int* __restrict__ idx,
                                               const float* __restrict__ tok,
                                               const float* __restrict__ pos,
                                               float* __restrict__ h) {
    int row = blockIdx.x;
    int s = row % SEQ;
    int t = idx[row];
    const float4* te = (const float4*)(tok + (size_t)t * EMB);
    const float4* pe = (const float4*)(pos + (size_t)s * EMB);
    float4* o = (float4*)(h + (size_t)row * EMB);
    int i = threadIdx.x;
    float4 a = te[i], b = pe[i];
    o[i] = make_float4(a.x + b.x, a.y + b.y, a.z + b.z, a.w + b.w);
}

// ---------------- layernorm (dual-precision output) ----------------
__global__ __launch_bounds__(256) void ln_k(const float* __restrict__ x,
                                            const float* __restrict__ g,
                                            const float* __restrict__ b,
                                            float* __restrict__ of,
                                            ushort* __restrict__ ob) {
    int row = blockIdx.x;
    int t = threadIdx.x;
    const float* xr = x + (size_t)row * EMB;
    float a0 = xr[t], a1 = xr[t + 256], a2 = xr[t + 512];
    __shared__ float red[4];
    float s = waveRedSum(a0 + a1 + a2);
    if ((t & 63) == 0) red[t >> 6] = s;
    __syncthreads();
    float mean = (red[0] + red[1] + red[2] + red[3]) * (1.0f / EMB);
    float d0 = a0 - mean, d1 = a1 - mean, d2 = a2 - mean;
    float vv = waveRedSum(d0 * d0 + d1 * d1 + d2 * d2);
    __syncthreads();
    if ((t & 63) == 0) red[t >> 6] = vv;
    __syncthreads();
    float var = (red[0] + red[1] + red[2] + red[3]) * (1.0f / EMB);
    float rstd = rsqrtf(var + EPSLN);
    float v0 = d0 * rstd * g[t]       + b[t];
    float v1 = d1 * rstd * g[t + 256] + b[t + 256];
    float v2 = d2 * rstd * g[t + 512] + b[t + 512];
    size_t base = (size_t)row * EMB;
    if (of) { of[base + t] = v0; of[base + t + 256] = v1; of[base + t + 512] = v2; }
    if (ob) { ob[base + t] = f2bf(v0); ob[base + t + 256] = f2bf(v1); ob[base + t + 512] = f2bf(v2); }
}

// ---------------- weight transpose+convert: W[z][K][N] f32 -> Wt[z][NP][K] bf16 ----
__global__ __launch_bounds__(256) void wtrans_k(const float* __restrict__ W,
                                                ushort* __restrict__ Wt,
                                                int K, int N, int NP,
                                                long zsW, long zsWt) {
    __shared__ float tile[32][33];
    int zb = blockIdx.z;
    int n0 = blockIdx.x * 32, k0 = blockIdx.y * 32;
    int tx = threadIdx.x & 31, ty = threadIdx.x >> 5;   // ty: 0..7
    const float* Wz = W + (size_t)zb * zsW;
    ushort* Wtz = Wt + (size_t)zb * zsWt;
#pragma unroll
    for (int j = 0; j < 4; ++j) {
        int k = k0 + ty + j * 8, n = n0 + tx;
        tile[ty + j * 8][tx] = (k < K && n < N) ? Wz[(size_t)k * N + n] : 0.f;
    }
    __syncthreads();
#pragma unroll
    for (int j = 0; j < 4; ++j) {
        int n = n0 + ty + j * 8, k = k0 + tx;
        if (n < NP && k < K) Wtz[(size_t)n * K + k] = f2bf(tile[tx][ty + j * 8]);
    }
}

// ---------------- qkv bias concat ----------------
__global__ __launch_bounds__(256) void bconcat_k(const float* __restrict__ bq,
                                                 const float* __restrict__ bk,
                                                 const float* __restrict__ bv,
                                                 float* __restrict__ bqkv) {
    int i = blockIdx.x * 256 + threadIdx.x;
    if (i >= LAYERS * QKVN) return;
    int l = i / QKVN, c = i % QKVN;
    float v = (c < EMB) ? bq[l * EMB + c] : (c < 2 * EMB) ? bk[l * EMB + c - EMB] : bv[l * EMB + c - 2 * EMB];
    bqkv[i] = v;
}

// ---------------- bf16 MFMA GEMM (m97 structure): C[M,N] = A[M,K] @ Wt[N,K]^T ----
// 128x128 tile, BK=32, 4 waves, 16x16x32 bf16 MFMA, global_load_lds width 16.
// flags: 1 = gelu, 2 = bf16 output
__global__ __launch_bounds__(256) void gemm_mfma_k(const ushort* __restrict__ A,
                                                   const ushort* __restrict__ Wt,
                                                   const float* __restrict__ bias,
                                                   const float* __restrict__ Res,
                                                   void* __restrict__ Cout,
                                                   int M, int N, int K, int ldc, int flags) {
    __shared__ ushort As[128 * 32];
    __shared__ ushort Bs[128 * 32];
    const int gx = (N + 127) >> 7;
    const int nwg = gx * (M >> 7);
    int bid = blockIdx.x;
    if ((nwg & 7) == 0) {                       // XCD-aware swizzle (bijective: nwg % 8 == 0)
        int cpx = nwg >> 3;
        bid = (bid & 7) * cpx + (bid >> 3);
    }
    const int row0 = (bid / gx) << 7;
    const int col0 = (bid % gx) << 7;

    const int t = threadIdx.x;
    const int lane = t & 63, w = t >> 6;
    const int wr = (w >> 1) << 6;               // wave row offset in tile
    const int wc = (w & 1) << 6;                // wave col offset in tile

    // staging: wave w covers rows [w*16, w*16+16) (issue 0) and +64 (issue 1)
    const ushort* aSrc0 = A  + (size_t)(row0 + w * 16 + (lane >> 2)) * K + (lane & 3) * 8;
    const ushort* aSrc1 = aSrc0 + (size_t)64 * K;
    const ushort* bSrc0 = Wt + (size_t)(col0 + w * 16 + (lane >> 2)) * K + (lane & 3) * 8;
    const ushort* bSrc1 = bSrc0 + (size_t)64 * K;
    ushort* aDst0 = &As[w * 512];
    ushort* bDst0 = &Bs[w * 512];

    f32x4 acc[4][4] = {};
    const int ko = (lane >> 4) * 8;             // fragment k offset
    const int fr = lane & 15;                   // fragment row/col

    for (int k0 = 0; k0 < K; k0 += 32) {
        gload_lds16(aSrc0 + k0, aDst0);
        gload_lds16(aSrc1 + k0, aDst0 + 2048);
        gload_lds16(bSrc0 + k0, bDst0);
        gload_lds16(bSrc1 + k0, bDst0 + 2048);
        __syncthreads();
        short8 af[4], bf[4];
#pragma unroll
        for (int mi = 0; mi < 4; ++mi)
            af[mi] = *(const short8*)&As[(wr + mi * 16 + fr) * 32 + ko];
#pragma unroll
        for (int ni = 0; ni < 4; ++ni)
            bf[ni] = *(const short8*)&Bs[(wc + ni * 16 + fr) * 32 + ko];
#pragma unroll
        for (int mi = 0; mi < 4; ++mi)
#pragma unroll
            for (int ni = 0; ni < 4; ++ni)
                acc[mi][ni] = __builtin_amdgcn_mfma_f32_16x16x32_bf16(af[mi], bf[ni], acc[mi][ni], 0, 0, 0);
        __syncthreads();
    }

    const int gelu = flags & 1, obf = flags & 2;
#pragma unroll
    for (int mi = 0; mi < 4; ++mi) {
#pragma unroll
        for (int ni = 0; ni < 4; ++ni) {
            int col = col0 + wc + ni * 16 + fr;
            if (col >= N) continue;
            int rbase = row0 + wr + mi * 16 + ((lane >> 4) << 2);
            float bv = bias ? bias[col] : 0.f;
            f32x4 v = acc[mi][ni];
#pragma unroll
            for (int r = 0; r < 4; ++r) {
                int row = rbase + r;
                float val = v[r] + bv;
                if (gelu) val = geluf(val);
                if (Res) val += Res[(size_t)row * ldc + col];
                if (obf) ((ushort*)Cout)[(size_t)row * ldc + col] = f2bf(val);
                else     ((float*)Cout)[(size_t)row * ldc + col] = val;
            }
        }
    }
}

// ---------------- fp32 tiled GEMM (fallback path) ----------------
__global__ __launch_bounds__(256) void gemm_k(const float* __restrict__ A,
                                              const float* __restrict__ Bw,
                                              const float* __restrict__ bias,
                                              const float* __restrict__ Res,
                                              float* __restrict__ C,
                                              int N, int K, int applyGelu) {
    __shared__ float Ast[16][68];
    __shared__ float Bs[16][64];
    const int t = threadIdx.x;
    const int row0 = blockIdx.y * 64, col0 = blockIdx.x * 64;
    const int tx = t & 15, ty = t >> 4;
    const int arow = t >> 2, ak = (t & 3) << 2;
    const int brow = t >> 4, bc = (t & 15) << 2;
    float acc[4][4] = {};
    const float* aptr = A + (size_t)(row0 + arow) * K + ak;
    const int bcol = col0 + bc;
    for (int k0 = 0; k0 < K; k0 += 16) {
        float4 av = *(const float4*)(aptr + k0);
        Ast[ak + 0][arow] = av.x;
        Ast[ak + 1][arow] = av.y;
        Ast[ak + 2][arow] = av.z;
        Ast[ak + 3][arow] = av.w;
        const float* bp = Bw + (size_t)(k0 + brow) * N + bcol;
        float4 bv;
        if (bcol + 3 < N) bv = *(const float4*)bp;
        else {
            bv.x = (bcol + 0 < N) ? bp[0] : 0.f;
            bv.y = (bcol + 1 < N) ? bp[1] : 0.f;
            bv.z = (bcol + 2 < N) ? bp[2] : 0.f;
            bv.w = (bcol + 3 < N) ? bp[3] : 0.f;
        }
        *(float4*)&Bs[brow][bc] = bv;
        __syncthreads();
#pragma unroll
        for (int kk = 0; kk < 16; ++kk) {
            float4 a = *(const float4*)&Ast[kk][ty << 2];
            float4 b = *(const float4*)&Bs[kk][tx << 2];
            acc[0][0] += a.x * b.x; acc[0][1] += a.x * b.y; acc[0][2] += a.x * b.z; acc[0][3] += a.x * b.w;
            acc[1][0] += a.y * b.x; acc[1][1] += a.y * b.y; acc[1][2] += a.y * b.z; acc[1][3] += a.y * b.w;
            acc[2][0] += a.z * b.x; acc[2][1] += a.z * b.y; acc[2][2] += a.z * b.z; acc[2][3] += a.z * b.w;
            acc[3][0] += a.w * b.x; acc[3][1] += a.w * b.y; acc[3][2] += a.w * b.z; acc[3][3] += a.w * b.w;
        }
        __syncthreads();
    }
#pragma unroll
    for (int i = 0; i < 4; ++i) {
        int row = row0 + (ty << 2) + i;
#pragma unroll
        for (int j = 0; j < 4; ++j) {
            int col = col0 + (tx << 2) + j;
            if (col < N) {
                float v = acc[i][j];
                if (bias) v += bias[col];
                if (applyGelu) v = geluf(v);
                if (Res) v += Res[(size_t)row * N + col];
                C[(size_t)row * N + col] = v;
            }
        }
    }
}

// ---------------- causal attention, one block per (b, h, q-row) ----------------
__global__ __launch_bounds__(256) void attn_k(const float* __restrict__ Q,
                                              const float* __restrict__ Kb,
                                              const float* __restrict__ Vb,
                                              int ld,
                                              float* __restrict__ Of,
                                              ushort* __restrict__ Ob) {
    int blk = blockIdx.x;
    int qi = blk & (SEQ - 1);
    int hh = (blk >> 10) % NHEAD;
    int bb = blk / (SEQ * NHEAD);
    int t = threadIdx.x;
    int lane = t & 63, wave = t >> 6;
    __shared__ float qs[HDIM];
    __shared__ float sc[SEQ];
    __shared__ float red[4], red2[4];
    __shared__ float vred[4][HDIM];
    const size_t headOff = (size_t)bb * SEQ * ld + (size_t)hh * HDIM;
    if (t < HDIM) qs[t] = Q[headOff + (size_t)qi * ld + t] * 0.125f;
    __syncthreads();
    int nk = qi + 1;
    for (int kk = wave; kk < nk; kk += 4) {
        float kv = Kb[headOff + (size_t)kk * ld + lane];
        float p = waveRedSum(qs[lane] * kv);
        if (lane == 0) sc[kk] = p;
    }
    __syncthreads();
    float m = -1e30f;
    for (int kk = t; kk < nk; kk += 256) m = fmaxf(m, sc[kk]);
    m = waveRedMax(m);
    if (lane == 0) red[wave] = m;
    __syncthreads();
    m = fmaxf(fmaxf(red[0], red[1]), fmaxf(red[2], red[3]));
    float ssum = 0.f;
    for (int kk = t; kk < nk; kk += 256) {
        float p = __expf(sc[kk] - m);
        sc[kk] = p;
        ssum += p;
    }
    ssum = waveRedSum(ssum);
    if (lane == 0) red2[wave] = ssum;
    __syncthreads();
    float inv = 1.0f / (red2[0] + red2[1] + red2[2] + red2[3]);
    int d = t & 63, chunk = t >> 6;
    float acc = 0.f;
    for (int kk = chunk; kk < nk; kk += 4)
        acc += sc[kk] * Vb[headOff + (size_t)kk * ld + d];
    vred[chunk][d] = acc;
    __syncthreads();
    if (t < HDIM) {
        float r = (vred[0][t] + vred[1][t] + vred[2][t] + vred[3][t]) * inv;
        size_t oOff = ((size_t)bb * SEQ + qi) * EMB + (size_t)hh * HDIM + t;
        if (Ob) Ob[oOff] = f2bf(r);
        else    Of[oOff] = r;
    }
}

// ---------------- launch ----------------
extern "C" void kernel_launch(void* const* d_in, const int* in_sizes, int n_in,
                              void* d_out, int out_size, void* d_ws, size_t ws_size,
                              hipStream_t stream) {
    const int*   idx  = (const int*)d_in[0];
    const float* tok  = (const float*)d_in[1];
    const float* pos  = (const float*)d_in[2];
    const float* ln1g = (const float*)d_in[3];
    const float* ln1b = (const float*)d_in[4];
    const float* wq   = (const float*)d_in[5];
    const float* bq   = (const float*)d_in[6];
    const float* wk   = (const float*)d_in[7];
    const float* bk   = (const float*)d_in[8];
    const float* wv   = (const float*)d_in[9];
    const float* bv   = (const float*)d_in[10];
    const float* wo   = (const float*)d_in[11];
    const float* bo   = (const float*)d_in[12];
    const float* ln2g = (const float*)d_in[13];
    const float* ln2b = (const float*)d_in[14];
    const float* w1   = (const float*)d_in[15];
    const float* b1   = (const float*)d_in[16];
    const float* w2   = (const float*)d_in[17];
    const float* b2   = (const float*)d_in[18];
    const float* lnfg = (const float*)d_in[19];
    const float* lnfb = (const float*)d_in[20];
    const float* wout = (const float*)d_in[21];
    float* out = (float*)d_out;

    // ---- workspace layout (bf16 MFMA path) ----
    char* p = (char*)d_ws;
    auto alloc = [&](size_t bytes) { char* r = p; p += (bytes + 255) & ~(size_t)255; return r; };
    ushort* wtqkv = (ushort*)alloc((size_t)LAYERS * QKVN * EMB * 2);
    ushort* wto   = (ushort*)alloc((size_t)LAYERS * EMB * EMB * 2);
    ushort* wt1   = (ushort*)alloc((size_t)LAYERS * FFDIM * EMB * 2);
    ushort* wt2   = (ushort*)alloc((size_t)LAYERS * EMB * FFDIM * 2);
    ushort* wtout = (ushort*)alloc((size_t)VPAD * EMB * 2);
    float*  bqkv  = (float*)alloc((size_t)LAYERS * QKVN * 4);
    float*  h     = (float*)alloc((size_t)MTOK * EMB * 4);
    ushort* xb    = (ushort*)alloc((size_t)MTOK * EMB * 2);
    float*  xqkv  = (float*)alloc((size_t)MTOK * QKVN * 4);
    ushort* aob   = (ushort*)alloc((size_t)MTOK * EMB * 2);
    ushort* ffb   = (ushort*)alloc((size_t)MTOK * FFDIM * 2);
    size_t need = (size_t)(p - (char*)d_ws);

    if (ws_size >= need) {
        // ======== bf16 MFMA path ========
        // weight transpose+convert (7 launches, whole stack)
        wtrans_k<<<dim3(EMB / 32, EMB / 32, LAYERS), 256, 0, stream>>>(
            wq, wtqkv, EMB, EMB, EMB, (long)EMB * EMB, (long)QKVN * EMB);
        wtrans_k<<<dim3(EMB / 32, EMB / 32, LAYERS), 256, 0, stream>>>(
            wk, wtqkv + (size_t)EMB * EMB, EMB, EMB, EMB, (long)EMB * EMB, (long)QKVN * EMB);
        wtrans_k<<<dim3(EMB / 32, EMB / 32, LAYERS), 256, 0, stream>>>(
            wv, wtqkv + (size_t)2 * EMB * EMB, EMB, EMB, EMB, (long)EMB * EMB, (long)QKVN * EMB);
        wtrans_k<<<dim3(EMB / 32, EMB / 32, LAYERS), 256, 0, stream>>>(
            wo, wto, EMB, EMB, EMB, (long)EMB * EMB, (long)EMB * EMB);
        wtrans_k<<<dim3(FFDIM / 32, EMB / 32, LAYERS), 256, 0, stream>>>(
            w1, wt1, EMB, FFDIM, FFDIM, (long)EMB * FFDIM, (long)FFDIM * EMB);
        wtrans_k<<<dim3(EMB / 32, FFDIM / 32, LAYERS), 256, 0, stream>>>(
            w2, wt2, FFDIM, EMB, EMB, (long)FFDIM * EMB, (long)EMB * FFDIM);
        wtrans_k<<<dim3((VPAD + 31) / 32, EMB / 32, 1), 256, 0, stream>>>(
            wout, wtout, EMB, VOCAB, VPAD, 0, 0);
        bconcat_k<<<(LAYERS * QKVN + 255) / 256, 256, 0, stream>>>(bq, bk, bv, bqkv);

        embed_k<<<MTOK, 192, 0, stream>>>(idx, tok, pos, h);

        for (int l = 0; l < LAYERS; ++l) {
            ln_k<<<MTOK, 256, 0, stream>>>(h, ln1g + l * EMB, ln1b + l * EMB, nullptr, xb);
            gemm_mfma_k<<<(QKVN / 128) * (MTOK / 128), 256, 0, stream>>>(
                xb, wtqkv + (size_t)l * QKVN * EMB, bqkv + (size_t)l * QKVN, nullptr, xqkv,
                MTOK, QKVN, EMB, QKVN, 0);
            attn_k<<<BATCH * NHEAD * SEQ, 256, 0, stream>>>(
                xqkv, xqkv + EMB, xqkv + 2 * EMB, QKVN, nullptr, aob);
            gemm_mfma_k<<<(EMB / 128) * (MTOK / 128), 256, 0, stream>>>(
                aob, wto + (size_t)l * EMB * EMB, bo + (size_t)l * EMB, h, h,
                MTOK, EMB, EMB, EMB, 0);
            ln_k<<<MTOK, 256, 0, stream>>>(h, ln2g + l * EMB, ln2b + l * EMB, nullptr, xb);
            gemm_mfma_k<<<(FFDIM / 128) * (MTOK / 128), 256, 0, stream>>>(
                xb, wt1 + (size_t)l * FFDIM * EMB, b1 + (size_t)l * FFDIM, nullptr, ffb,
                MTOK, FFDIM, EMB, FFDIM, 1 | 2);
            gemm_mfma_k<<<(EMB / 128) * (MTOK / 128), 256, 0, stream>>>(
                ffb, wt2 + (size_t)l * EMB * FFDIM, b2 + (size_t)l * EMB, h, h,
                MTOK, EMB, FFDIM, EMB, 0);
        }
        ln_k<<<MTOK, 256, 0, stream>>>(h, lnfg, lnfb, nullptr, xb);
        gemm_mfma_k<<<(VPAD / 128) * (MTOK / 128), 256, 0, stream>>>(
            xb, wtout, nullptr, nullptr, out, MTOK, VOCAB, EMB, VOCAB, 0);
    } else {
        // ======== fp32 fallback path ========
        const size_t ME = (size_t)MTOK * EMB;
        float* fh  = (float*)d_ws;
        float* fx  = fh + ME;
        float* fq  = fx + ME;
        float* fk  = fq + ME;
        float* fv  = fk + ME;
        float* fao = fv + ME;
        float* fff = fao + ME;
        embed_k<<<MTOK, 192, 0, stream>>>(idx, tok, pos, fh);
        for (int l = 0; l < LAYERS; ++l) {
            const size_t wOff = (size_t)l * EMB * EMB;
            ln_k<<<MTOK, 256, 0, stream>>>(fh, ln1g + l * EMB, ln1b + l * EMB, fx, nullptr);
            gemm_k<<<dim3(EMB / 64, MTOK / 64), 256, 0, stream>>>(fx, wq + wOff, bq + l * EMB, nullptr, fq, EMB, EMB, 0);
            gemm_k<<<dim3(EMB / 64, MTOK / 64), 256, 0, stream>>>(fx, wk + wOff, bk + l * EMB, nullptr, fk, EMB, EMB, 0);
            gemm_k<<<dim3(EMB / 64, MTOK / 64), 256, 0, stream>>>(fx, wv + wOff, bv + l * EMB, nullptr, fv, EMB, EMB, 0);
            attn_k<<<BATCH * NHEAD * SEQ, 256, 0, stream>>>(fq, fk, fv, EMB, fao, nullptr);
            gemm_k<<<dim3(EMB / 64, MTOK / 64), 256, 0, stream>>>(fao, wo + wOff, bo + l * EMB, fh, fh, EMB, EMB, 0);
            ln_k<<<MTOK, 256, 0, stream>>>(fh, ln2g + l * EMB, ln2b + l * EMB, fx, nullptr);
            gemm_k<<<dim3(FFDIM / 64, MTOK / 64), 256, 0, stream>>>(fx, w1 + (size_t)l * EMB * FFDIM, b1 + (size_t)l * FFDIM, nullptr, fff, FFDIM, EMB, 1);
            gemm_k<<<dim3(EMB / 64, MTOK / 64), 256, 0, stream>>>(fff, w2 + (size_t)l * FFDIM * EMB, b2 + l * EMB, fh, fh, EMB, FFDIM, 0);
        }
        ln_k<<<MTOK, 256, 0, stream>>>(fh, lnfg, lnfb, fx, nullptr);
        gemm_k<<<dim3((VOCAB + 63) / 64, MTOK / 64), 256, 0, stream>>>(fx, wout, nullptr, nullptr, out, VOCAB, EMB, 0);
    }
}